// Round 6
// baseline (333.697 us; speedup 1.0000x reference)
//
#include <hip/hip_runtime.h>
#include <hip/hip_bf16.h>

// Swin block, B=32 H=W=56 C=128, ws=7 (N=49), nh=4 (hd=32), shift=3, hid=512.
// fp32 in/out. FULLY FUSED single kernel: LN1 + window attention + proj +
// shortcut + LN2 + MLP(gelu) + residual, all per-window (2048 blocks).
// Works because roll(-3) window gather == roll(+3) scatter target, and MLP is
// per-token -> x2 tile never leaves LDS.
// All GEMMs + QK^T + AV via mfma_f32_16x16x32_bf16 (fp32 accum).
// LDS overlays: x2s(fp32) over dead Q/K; hb over dead V^T; lnb over dead o-tile.

#define TOK  100352
#define NWIN 2048

typedef short short8  __attribute__((ext_vector_type(8)));
typedef short short4v __attribute__((ext_vector_type(4)));
typedef float f32x4   __attribute__((ext_vector_type(4)));

#define QKVW_OFF  0        // 384*128 bf16
#define PROJW_OFF 49152    // 128*128
#define W1_OFF    65536    // 512*128
#define W2_OFF    131072   // 128*512
#define BIAS_BYTE_OFF 393216  // biasT[4][64][64] fp32 (padded, 0 outside 49x49)

__device__ __forceinline__ short f2bs(float v) {
  __hip_bfloat16 h = __float2bfloat16(v);
  union { __hip_bfloat16 h; short s; } u; u.h = h; return u.s;
}
__device__ __forceinline__ float gelu_f(float v) {
  float u = v * (0.7978845608028654f + 0.03567740814f * v * v);
  return v * __builtin_amdgcn_rcpf(1.f + __expf(-2.f * u));
}

// ---------------- pre-pass: weights -> bf16, padded bias^T gather ----------------
__global__ __launch_bounds__(256) void conv_kernel(
    const float* __restrict__ qkvw, const float* __restrict__ projw,
    const float* __restrict__ w1,   const float* __restrict__ w2,
    const float* __restrict__ tab,  const int* __restrict__ ridx,
    __hip_bfloat16* __restrict__ wsb, float* __restrict__ biasT)
{
  int idx = blockIdx.x * 256 + threadIdx.x;
  if (idx < 49152)       wsb[QKVW_OFF + idx]          = __float2bfloat16(qkvw[idx]);
  else if (idx < 65536)  wsb[PROJW_OFF + idx - 49152] = __float2bfloat16(projw[idx - 49152]);
  else if (idx < 131072) wsb[W1_OFF + idx - 65536]    = __float2bfloat16(w1[idx - 65536]);
  else if (idx < 196608) wsb[W2_OFF + idx - 131072]   = __float2bfloat16(w2[idx - 131072]);
  else if (idx < 212992) {
    int i = idx - 196608;
    int h = i >> 12, m = (i >> 6) & 63, n = i & 63;   // biasT[h][m=key][n=query]
    biasT[i] = (m < 49 && n < 49) ? tab[ridx[n*49 + m]*4 + h] : 0.f;
  }
}

// ---------------- the fused Swin block kernel ----------------
__global__ __launch_bounds__(256) void swin_kernel(
    const float* __restrict__ x,
    const float* __restrict__ n1g, const float* __restrict__ n1b,
    const __hip_bfloat16* __restrict__ qkvwb, const float* __restrict__ qkvb,
    const float* __restrict__ biasT,
    const __hip_bfloat16* __restrict__ projwb, const float* __restrict__ projb,
    const float* __restrict__ n2g, const float* __restrict__ n2b,
    const __hip_bfloat16* __restrict__ w1b, const float* __restrict__ b1,
    const __hip_bfloat16* __restrict__ w2b, const float* __restrict__ b2,
    float* __restrict__ out)
{
  __shared__ alignas(16) __hip_bfloat16 hbuf[64][136];   // h tile -> o tile -> lnb
  __shared__ alignas(16) char dyn[59392];                // qk+vT -> x2s+hb
  __shared__ int tokrow[64];
  auto qk  = (__hip_bfloat16 (*)[2][64][40])dyn;          // [4][2][64][40] 40960 B
  auto vT  = (__hip_bfloat16 (*)[32][72])(dyn + 40960);   // [4][32][72]    18432 B
  auto x2s = (float (*)[132])dyn;                         // [64][132] fp32 33792 B
  auto hb  = (__hip_bfloat16 (*)[136])(dyn + 40960);      // [64][136]      17408 B

  const int tid = threadIdx.x, wave = tid >> 6, lane = tid & 63;
  const int l15 = lane & 15, quad = lane >> 4;
  const int b = blockIdx.x >> 6, wi = (blockIdx.x >> 3) & 7, wj = blockIdx.x & 7;

  // ---- phase 1: LN1 (roll -3 gather). All global loads hoisted ahead of the
  //      reduction chains (26 outstanding/wave vs 2). tokrow cached for epilogues.
  {
    float va[13], vb[13];
    #pragma unroll
    for (int i = 0; i < 13; ++i) {
      int n = wave + i*4; int nc = n < 49 ? n : 48;
      int r = nc / 7, c = nc - r*7;
      int si = wi*7 + r + 3; if (si >= 56) si -= 56;
      int sj = wj*7 + c + 3; if (sj >= 56) sj -= 56;
      int trow = (b*3136 + si*56 + sj) * 128;
      if (lane == 0 && n < 49) tokrow[n] = trow;
      const float* xr = x + trow;
      va[i] = xr[lane]; vb[i] = xr[lane + 64];
    }
    float g0 = n1g[lane], g1 = n1g[lane+64], e0 = n1b[lane], e1 = n1b[lane+64];
    #pragma unroll
    for (int i = 0; i < 13; ++i) {
      int n = wave + i*4;
      if (n < 49) {
        float s = va[i] + vb[i], sq = va[i]*va[i] + vb[i]*vb[i];
        #pragma unroll
        for (int off = 32; off > 0; off >>= 1) {
          s  += __shfl_xor(s,  off);
          sq += __shfl_xor(sq, off);
        }
        float mean = s * 0.0078125f;
        float var  = sq * 0.0078125f - mean*mean;
        float rstd = rsqrtf(var + 1e-5f);
        hbuf[n][lane]    = __float2bfloat16((va[i]-mean)*rstd*g0 + e0);
        hbuf[n][lane+64] = __float2bfloat16((vb[i]-mean)*rstd*g1 + e1);
      }
    }
  }
  __syncthreads();

  // ---- phase 2: QKV GEMM. Q/K operand-swapped (D[f][m]) -> vector LDS writes;
  //      V natural (D[m][f]) -> writes V^T directly. ----
  {
    const int which = wave >> 1;
    const int fb    = (wave & 1) * 64;
    const int vb    = wave * 32;
    f32x4 asw[4][4] = {};
    f32x4 aor[4][2] = {};
    #pragma unroll
    for (int ks = 0; ks < 4; ++ks) {
      short8 hf[4];
      #pragma unroll
      for (int mt = 0; mt < 4; ++mt)
        hf[mt] = *(const short8*)(&hbuf[mt*16 + l15][ks*32 + quad*8]);
      #pragma unroll
      for (int ft = 0; ft < 4; ++ft) {
        short8 wf = *(const short8*)(qkvwb + (which*128 + fb + ft*16 + l15)*128 + ks*32 + quad*8);
        #pragma unroll
        for (int mt = 0; mt < 4; ++mt)
          asw[ft][mt] = __builtin_amdgcn_mfma_f32_16x16x32_bf16(wf, hf[mt], asw[ft][mt], 0, 0, 0);
      }
      #pragma unroll
      for (int nt = 0; nt < 2; ++nt) {
        short8 wf = *(const short8*)(qkvwb + (256 + vb + nt*16 + l15)*128 + ks*32 + quad*8);
        #pragma unroll
        for (int mt = 0; mt < 4; ++mt)
          aor[mt][nt] = __builtin_amdgcn_mfma_f32_16x16x32_bf16(hf[mt], wf, aor[mt][nt], 0, 0, 0);
      }
    }
    const float qs = (which == 0) ? 0.17677669529663687f : 1.0f;
    #pragma unroll
    for (int ft = 0; ft < 4; ++ft) {
      int fo = fb + ft*16 + quad*4;
      int hh = fo >> 5, d0 = fo & 31;
      float bb[4];
      #pragma unroll
      for (int r = 0; r < 4; ++r) bb[r] = qkvb[which*128 + fo + r];
      #pragma unroll
      for (int mt = 0; mt < 4; ++mt) {
        int m = mt*16 + l15;
        if (m < 49) {
          short4v pk;
          #pragma unroll
          for (int r = 0; r < 4; ++r) pk[r] = f2bs((asw[ft][mt][r] + bb[r]) * qs);
          *(short4v*)(&qk[hh][which][m][d0]) = pk;
        }
      }
    }
    #pragma unroll
    for (int nt = 0; nt < 2; ++nt) {
      int n = vb + nt*16 + l15;
      int hh = n >> 5, d = n & 31;
      float bia = qkvb[256 + n];
      #pragma unroll
      for (int mt = 0; mt < 4; ++mt) {
        int m0 = mt*16 + quad*4;
        short4v pk;
        #pragma unroll
        for (int r = 0; r < 4; ++r) {
          float v = (m0 + r < 49) ? (aor[mt][nt][r] + bia) : 0.f;
          pk[r] = f2bs(v);
        }
        *(short4v*)(&vT[hh][d][m0]) = pk;
      }
    }
  }
  __syncthreads();

  // ---- phase 3: attention, wave = head. S^T = K·Q^T, softmax over m,
  //      P -> LDS (overlays own head's Q/K), O = V^T·P^T -> hbuf o-tile. ----
  {
    const int h = wave;
    __hip_bfloat16* qbase = &qk[h][0][0][0];
    __hip_bfloat16* kbase = &qk[h][1][0][0];
    short8 kf[4], qf[4];
    #pragma unroll
    for (int mt = 0; mt < 4; ++mt) kf[mt] = *(const short8*)(kbase + (mt*16 + l15)*40 + quad*8);
    #pragma unroll
    for (int nt = 0; nt < 4; ++nt) qf[nt] = *(const short8*)(qbase + (nt*16 + l15)*40 + quad*8);
    f32x4 sacc[4][4] = {};
    #pragma unroll
    for (int mt = 0; mt < 4; ++mt)
      #pragma unroll
      for (int nt = 0; nt < 4; ++nt)
        sacc[mt][nt] = __builtin_amdgcn_mfma_f32_16x16x32_bf16(kf[mt], qf[nt], sacc[mt][nt], 0, 0, 0);

    const float* bT = biasT + h*4096;
    #pragma unroll
    for (int mt = 0; mt < 4; ++mt)
      #pragma unroll
      for (int nt = 0; nt < 4; ++nt)
        #pragma unroll
        for (int r = 0; r < 4; ++r)
          sacc[mt][nt][r] += bT[(mt*16 + quad*4 + r)*64 + nt*16 + l15];

    __hip_bfloat16* pb = qbase;   // P[n][m], stride 72, overlays Q+K (5120 el)
    #pragma unroll
    for (int nt = 0; nt < 4; ++nt) {
      float mx = -1e30f;
      #pragma unroll
      for (int mt = 0; mt < 3; ++mt)
        #pragma unroll
        for (int r = 0; r < 4; ++r) mx = fmaxf(mx, sacc[mt][nt][r]);
      mx = fmaxf(mx, (quad == 0) ? sacc[3][nt][0] : -1e30f);
      mx = fmaxf(mx, __shfl_xor(mx, 16));
      mx = fmaxf(mx, __shfl_xor(mx, 32));
      float sum = 0.f;
      #pragma unroll
      for (int mt = 0; mt < 3; ++mt)
        #pragma unroll
        for (int r = 0; r < 4; ++r) {
          float e = __expf(sacc[mt][nt][r] - mx);
          sacc[mt][nt][r] = e; sum += e;
        }
      {
        float e = (quad == 0) ? __expf(sacc[3][nt][0] - mx) : 0.f;
        sacc[3][nt][0] = e; sacc[3][nt][1] = 0.f; sacc[3][nt][2] = 0.f; sacc[3][nt][3] = 0.f;
        sum += e;
      }
      sum += __shfl_xor(sum, 16);
      sum += __shfl_xor(sum, 32);
      float inv = 1.f / sum;
      int n = nt*16 + l15;
      #pragma unroll
      for (int mt = 0; mt < 4; ++mt) {
        short4v pk;
        #pragma unroll
        for (int r = 0; r < 4; ++r) pk[r] = f2bs(sacc[mt][nt][r] * inv);
        *(short4v*)(pb + n*72 + mt*16 + quad*4) = pk;
      }
    }

    f32x4 oacc[2][4] = {};
    #pragma unroll
    for (int kt = 0; kt < 2; ++kt) {
      short8 vf[2], pf[4];
      #pragma unroll
      for (int dt = 0; dt < 2; ++dt)
        vf[dt] = *(const short8*)(&vT[h][dt*16 + l15][kt*32 + quad*8]);
      #pragma unroll
      for (int nc = 0; nc < 4; ++nc)
        pf[nc] = *(const short8*)(pb + (nc*16 + l15)*72 + kt*32 + quad*8);
      #pragma unroll
      for (int dt = 0; dt < 2; ++dt)
        #pragma unroll
        for (int nc = 0; nc < 4; ++nc)
          oacc[dt][nc] = __builtin_amdgcn_mfma_f32_16x16x32_bf16(vf[dt], pf[nc], oacc[dt][nc], 0, 0, 0);
    }
    #pragma unroll
    for (int dt = 0; dt < 2; ++dt)
      #pragma unroll
      for (int nc = 0; nc < 4; ++nc) {
        int n = nc*16 + l15;
        if (n < 49) {
          short4v pk;
          #pragma unroll
          for (int r = 0; r < 4; ++r) pk[r] = f2bs(oacc[dt][nc][r]);
          *(short4v*)(&hbuf[n][h*32 + dt*16 + quad*4]) = pk;
        }
      }
  }
  __syncthreads();

  // ---- phase 4: proj + shortcut -> x2s (LDS fp32; overlays dead Q/K) ----
  {
    const int ncol0 = wave * 32;
    float xv[2][4][4];
    #pragma unroll
    for (int nt = 0; nt < 2; ++nt) {
      int n = ncol0 + nt*16 + l15;
      #pragma unroll
      for (int mt = 0; mt < 4; ++mt)
        #pragma unroll
        for (int r = 0; r < 4; ++r) {
          int m = mt*16 + quad*4 + r;
          xv[nt][mt][r] = (m < 49) ? x[tokrow[m] + n] : 0.f;
        }
    }
    f32x4 acc[4][2] = {};
    #pragma unroll
    for (int ks = 0; ks < 4; ++ks) {
      short8 af[4];
      #pragma unroll
      for (int mt = 0; mt < 4; ++mt)
        af[mt] = *(const short8*)(&hbuf[mt*16 + l15][ks*32 + quad*8]);
      #pragma unroll
      for (int nt = 0; nt < 2; ++nt) {
        short8 bf = *(const short8*)(projwb + (ncol0 + nt*16 + l15)*128 + ks*32 + quad*8);
        #pragma unroll
        for (int mt = 0; mt < 4; ++mt)
          acc[mt][nt] = __builtin_amdgcn_mfma_f32_16x16x32_bf16(af[mt], bf, acc[mt][nt], 0, 0, 0);
      }
    }
    #pragma unroll
    for (int nt = 0; nt < 2; ++nt) {
      int n = ncol0 + nt*16 + l15;
      float pbv = projb[n];
      #pragma unroll
      for (int mt = 0; mt < 4; ++mt)
        #pragma unroll
        for (int r = 0; r < 4; ++r) {
          int m = mt*16 + quad*4 + r;
          if (m < 49) x2s[m][n] = acc[mt][nt][r] + pbv + xv[nt][mt][r];
        }
    }
  }
  __syncthreads();

  // ---- phase 5: LN2 from x2s -> hbuf (lnb; o-tile dead) ----
  {
    float v0a[13], v1a[13];
    #pragma unroll
    for (int i = 0; i < 13; ++i) {
      int t = wave + i*4; int tc = t < 49 ? t : 48;
      v0a[i] = x2s[tc][lane]; v1a[i] = x2s[tc][lane+64];
    }
    float g0 = n2g[lane], g1 = n2g[lane+64], e0 = n2b[lane], e1 = n2b[lane+64];
    #pragma unroll
    for (int i = 0; i < 13; ++i) {
      int t = wave + i*4;
      if (t < 49) {
        float s = v0a[i] + v1a[i], sq = v0a[i]*v0a[i] + v1a[i]*v1a[i];
        #pragma unroll
        for (int off = 32; off > 0; off >>= 1) {
          s  += __shfl_xor(s,  off);
          sq += __shfl_xor(sq, off);
        }
        float mean = s * 0.0078125f;
        float var  = sq * 0.0078125f - mean*mean;
        float rstd = rsqrtf(var + 1e-5f);
        hbuf[t][lane]    = __float2bfloat16((v0a[i]-mean)*rstd*g0 + e0);
        hbuf[t][lane+64] = __float2bfloat16((v1a[i]-mean)*rstd*g1 + e1);
      }
    }
  }
  __syncthreads();

  // ---- phase 6: MLP, hidden dim in 4 chunks of 128 (hb overlays dead V^T) ----
  f32x4 acc2[4][2] = {};
  for (int chunk = 0; chunk < 4; ++chunk) {
    // GEMM1 chunk: D[j][m] swapped; wave covers 32 j's
    {
      const int jb = chunk*128 + wave*32;
      f32x4 acc1[2][4] = {};
      #pragma unroll
      for (int ks = 0; ks < 4; ++ks) {
        short8 lf[4];
        #pragma unroll
        for (int mt = 0; mt < 4; ++mt)
          lf[mt] = *(const short8*)(&hbuf[mt*16 + l15][ks*32 + quad*8]);
        #pragma unroll
        for (int jt = 0; jt < 2; ++jt) {
          short8 wf = *(const short8*)(w1b + (jb + jt*16 + l15)*128 + ks*32 + quad*8);
          #pragma unroll
          for (int mt = 0; mt < 4; ++mt)
            acc1[jt][mt] = __builtin_amdgcn_mfma_f32_16x16x32_bf16(wf, lf[mt], acc1[jt][mt], 0, 0, 0);
        }
      }
      #pragma unroll
      for (int jt = 0; jt < 2; ++jt) {
        int jg = jb + jt*16 + quad*4;          // global j for bias
        int loc = wave*32 + jt*16 + quad*4;    // chunk-local col in hb
        float bb[4];
        #pragma unroll
        for (int r = 0; r < 4; ++r) bb[r] = b1[jg + r];
        #pragma unroll
        for (int mt = 0; mt < 4; ++mt) {
          int m = mt*16 + l15;
          short4v pk;
          #pragma unroll
          for (int r = 0; r < 4; ++r) pk[r] = f2bs(gelu_f(acc1[jt][mt][r] + bb[r]));
          *(short4v*)(&hb[m][loc]) = pk;
        }
      }
    }
    __syncthreads();
    // GEMM2 partial: D[m][f]; wave covers 32 f's; K-chunk 128
    {
      #pragma unroll
      for (int ks = 0; ks < 4; ++ks) {
        short8 af[4];
        #pragma unroll
        for (int mt = 0; mt < 4; ++mt)
          af[mt] = *(const short8*)(&hb[mt*16 + l15][ks*32 + quad*8]);
        #pragma unroll
        for (int nt = 0; nt < 2; ++nt) {
          short8 wf = *(const short8*)(w2b + (wave*32 + nt*16 + l15)*512 + chunk*128 + ks*32 + quad*8);
          #pragma unroll
          for (int mt = 0; mt < 4; ++mt)
            acc2[mt][nt] = __builtin_amdgcn_mfma_f32_16x16x32_bf16(af[mt], wf, acc2[mt][nt], 0, 0, 0);
        }
      }
    }
    if (chunk < 3) __syncthreads();
  }

  // ---- phase 7: out = acc2 + b2 + x2 (residual from LDS), scatter via tokrow ----
  {
    #pragma unroll
    for (int nt = 0; nt < 2; ++nt) {
      int f = wave*32 + nt*16 + l15;
      float bb = b2[f];
      #pragma unroll
      for (int mt = 0; mt < 4; ++mt)
        #pragma unroll
        for (int r = 0; r < 4; ++r) {
          int m = mt*16 + quad*4 + r;
          if (m < 49) out[tokrow[m] + f] = acc2[mt][nt][r] + bb + x2s[m][f];
        }
    }
  }
}

extern "C" void kernel_launch(void* const* d_in, const int* in_sizes, int n_in,
                              void* d_out, int out_size, void* d_ws, size_t ws_size,
                              hipStream_t stream) {
  const float* x     = (const float*)d_in[0];
  const float* n1g   = (const float*)d_in[3];
  const float* n1b   = (const float*)d_in[4];
  const float* qkvw  = (const float*)d_in[5];
  const float* qkvb  = (const float*)d_in[6];
  const float* tab   = (const float*)d_in[7];
  const int*   ridx  = (const int*)d_in[8];
  const float* projw = (const float*)d_in[9];
  const float* projb = (const float*)d_in[10];
  const float* n2g   = (const float*)d_in[11];
  const float* n2b   = (const float*)d_in[12];
  const float* w1    = (const float*)d_in[13];
  const float* b1    = (const float*)d_in[14];
  const float* w2    = (const float*)d_in[15];
  const float* b2    = (const float*)d_in[16];
  float* outp = (float*)d_out;

  __hip_bfloat16* wsb = (__hip_bfloat16*)d_ws;
  float* biasT = (float*)((char*)d_ws + BIAS_BYTE_OFF);

  hipLaunchKernelGGL(conv_kernel, dim3(832), dim3(256), 0, stream,
                     qkvw, projw, w1, w2, tab, ridx, wsb, biasT);
  hipLaunchKernelGGL(swin_kernel, dim3(NWIN), dim3(256), 0, stream,
                     x, n1g, n1b, wsb + QKVW_OFF, qkvb, biasT, wsb + PROJW_OFF, projb,
                     n2g, n2b, wsb + W1_OFF, b1, wsb + W2_OFF, b2, outp);
}